// Round 1
// baseline (4613.423 us; speedup 1.0000x reference)
//
#include <hip/hip_runtime.h>

#define K_DIM 128

// ---------------------------------------------------------------------------
// Edge-parallel scatter-add: 32 threads per edge, each handling 4 floats.
// msg[dst] += h[src] (atomics), deg[dst] += 1.
// ---------------------------------------------------------------------------
__global__ __launch_bounds__(256)
void scatter_add_kernel(const float* __restrict__ h,
                        const int* __restrict__ src,
                        const int* __restrict__ dst,
                        float* __restrict__ msg,
                        float* __restrict__ deg,
                        int nE)
{
    long tid = (long)blockIdx.x * blockDim.x + threadIdx.x;
    int e = (int)(tid >> 5);
    int c = (int)(tid & 31);
    if (e >= nE) return;
    int s = src[e];
    int d = dst[e];
    float4 v = reinterpret_cast<const float4*>(h + (long)s * K_DIM)[c];
    float* o = msg + (long)d * K_DIM + c * 4;
    atomicAdd(o + 0, v.x);
    atomicAdd(o + 1, v.y);
    atomicAdd(o + 2, v.z);
    atomicAdd(o + 3, v.w);
    if (c == 0) atomicAdd(deg + d, 1.0f);
}

// ---------------------------------------------------------------------------
// Fused SAGE layer GEMM:
//   out[i][j] = act( sum_k h[i][k]*Wself[j][k]
//                  + sum_k (msg[i][k]/max(deg[i],1))*Wneigh[j][k] + b[j] )
// K = 128 fixed. NCOL = 128 or 64. Block: 256 threads, 64 rows per block.
// W is staged transposed ([k][j]) in LDS in k-chunks of 32; h/msg rows staged
// as [64][32] f32 tiles. Each thread computes 4 cols x RPT rows.
// LDS: 2*16KB (W) + 2*8KB (h/m) + rdg = ~48KB.
// ---------------------------------------------------------------------------
template<int NCOL, bool RELU>
__global__ __launch_bounds__(256)
void sage_gemm_kernel(const float* __restrict__ h,
                      const float* __restrict__ msg,
                      const float* __restrict__ deg,
                      const float* __restrict__ Wself,
                      const float* __restrict__ Wneigh,
                      const float* __restrict__ bias,
                      float* __restrict__ out,
                      int n)
{
    constexpr int K    = 128;
    constexpr int KC   = 32;            // k-chunk
    constexpr int ROWS = 64;            // rows per block
    constexpr int CT   = NCOL / 4;      // col-threads (32 or 16)
    constexpr int RG   = 256 / CT;      // row-groups (8 or 16)
    constexpr int RPT  = ROWS / RG;     // rows per thread (8 or 4)

    __shared__ float Ws[KC][NCOL];
    __shared__ float Wn[KC][NCOL];
    __shared__ float hs[ROWS][KC];
    __shared__ float ms[ROWS][KC];
    __shared__ float rdg[ROWS];

    const int t   = threadIdx.x;
    const int ct  = t % CT;
    const int rg  = t / CT;
    const int c0  = ct * 4;
    const int row0 = blockIdx.x * ROWS;

    if (t < ROWS) {
        int gr = row0 + t;
        float d = (gr < n) ? deg[gr] : 1.0f;
        rdg[t] = 1.0f / fmaxf(d, 1.0f);
    }

    float acc[RPT][4];
    #pragma unroll
    for (int r = 0; r < RPT; ++r)
        #pragma unroll
        for (int cc = 0; cc < 4; ++cc) acc[r][cc] = 0.0f;

    for (int kc = 0; kc < K; kc += KC) {
        __syncthreads();   // previous compute done (also covers rdg on iter 0)

        // stage W chunk, transposed: Ws[kk][j] = Wself[j][kc+kk]
        for (int idx = t; idx < KC * NCOL; idx += 256) {
            int kk = idx / NCOL;
            int j  = idx - kk * NCOL;
            Ws[kk][j] = Wself[j * K + kc + kk];
            Wn[kk][j] = Wneigh[j * K + kc + kk];
        }
        // stage h and msg*rdeg (float4)
        for (int idx = t; idx < ROWS * (KC / 4); idx += 256) {
            int r  = idx / (KC / 4);
            int k4 = idx - r * (KC / 4);
            int gr = row0 + r;
            float4 hv = make_float4(0.f, 0.f, 0.f, 0.f);
            float4 mv = make_float4(0.f, 0.f, 0.f, 0.f);
            if (gr < n) {
                hv = reinterpret_cast<const float4*>(h   + (long)gr * K + kc)[k4];
                mv = reinterpret_cast<const float4*>(msg + (long)gr * K + kc)[k4];
                float rd = rdg[r];
                mv.x *= rd; mv.y *= rd; mv.z *= rd; mv.w *= rd;
            }
            reinterpret_cast<float4*>(&hs[r][0])[k4] = hv;
            reinterpret_cast<float4*>(&ms[r][0])[k4] = mv;
        }
        __syncthreads();

        // compute: per thread 4 cols x RPT rows
        #pragma unroll
        for (int kk = 0; kk < KC; kk += 4) {
            float wsv[4][4], wnv[4][4];
            #pragma unroll
            for (int i = 0; i < 4; ++i) {
                float4 a = *reinterpret_cast<const float4*>(&Ws[kk + i][c0]);
                float4 b = *reinterpret_cast<const float4*>(&Wn[kk + i][c0]);
                wsv[i][0] = a.x; wsv[i][1] = a.y; wsv[i][2] = a.z; wsv[i][3] = a.w;
                wnv[i][0] = b.x; wnv[i][1] = b.y; wnv[i][2] = b.z; wnv[i][3] = b.w;
            }
            #pragma unroll
            for (int r = 0; r < RPT; ++r) {
                float4 hv = reinterpret_cast<const float4*>(&hs[rg * RPT + r][0])[kk / 4];
                float4 mv = reinterpret_cast<const float4*>(&ms[rg * RPT + r][0])[kk / 4];
                float hvv[4] = {hv.x, hv.y, hv.z, hv.w};
                float mvv[4] = {mv.x, mv.y, mv.z, mv.w};
                #pragma unroll
                for (int cc = 0; cc < 4; ++cc) {
                    float a = acc[r][cc];
                    #pragma unroll
                    for (int i = 0; i < 4; ++i) {
                        a = fmaf(hvv[i], wsv[i][cc], a);
                        a = fmaf(mvv[i], wnv[i][cc], a);
                    }
                    acc[r][cc] = a;
                }
            }
        }
    }

    // epilogue
    #pragma unroll
    for (int r = 0; r < RPT; ++r) {
        int gr = row0 + rg * RPT + r;
        if (gr < n) {
            float4 o;
            float* op = reinterpret_cast<float*>(&o);
            #pragma unroll
            for (int cc = 0; cc < 4; ++cc) {
                float v = acc[r][cc] + bias[c0 + cc];
                if (RELU) v = fmaxf(v, 0.0f);
                op[cc] = v;
            }
            *reinterpret_cast<float4*>(out + (long)gr * NCOL + c0) = o;
        }
    }
}

// ---------------------------------------------------------------------------
// Launch: 3 layers of {memset, scatter, gemm}. Workspace layout (floats):
//   msgbuf: [0, 12.8M)      msg0 / msg1 / msg2 (zeroed per layer);
//                            h2 aliased at msgbuf+4.0M (beyond msg1/msg2 use)
//   degbuf: [12.8M, +102400)
//   h1:     [12.9M, +12.8M)
// Total ~98.1 MiB.
// ---------------------------------------------------------------------------
extern "C" void kernel_launch(void* const* d_in, const int* in_sizes, int n_in,
                              void* d_out, int out_size, void* d_ws, size_t ws_size,
                              hipStream_t stream)
{
    const float* feats  = (const float*)d_in[0];
    const int*   src0   = (const int*)d_in[1];
    const int*   dst0   = (const int*)d_in[2];
    const int*   src1   = (const int*)d_in[3];
    const int*   dst1   = (const int*)d_in[4];
    const int*   src2   = (const int*)d_in[5];
    const int*   dst2   = (const int*)d_in[6];
    // d_in[7..9] = n_dst scalars (device mem; values fixed by setup_inputs)
    const float* Wself0 = (const float*)d_in[10];
    const float* Wneigh0= (const float*)d_in[11];
    const float* b0     = (const float*)d_in[12];
    const float* Wself1 = (const float*)d_in[13];
    const float* Wneigh1= (const float*)d_in[14];
    const float* b1     = (const float*)d_in[15];
    const float* Wself2 = (const float*)d_in[16];
    const float* Wneigh2= (const float*)d_in[17];
    const float* b2     = (const float*)d_in[18];

    const int E0 = in_sizes[1];
    const int E1 = in_sizes[3];
    const int E2 = in_sizes[5];
    const int N1 = 100000;   // n_dst0
    const int N2 = 20000;    // n_dst1
    const int N3 = 5000;     // n_dst2

    float* ws     = (float*)d_ws;
    float* msgbuf = ws;                       // 12,800,000 floats
    float* degbuf = ws + 12800000;            // 102,400 floats
    float* h1     = degbuf + 102400;          // 12,800,000 floats
    float* h2     = msgbuf + 4000000;         // 2,560,000 floats (aliased)
    float* outp   = (float*)d_out;

    // ---- layer 0: 500K -> 100K, d 128->128, relu
    hipMemsetAsync(msgbuf, 0, (size_t)N1 * K_DIM * sizeof(float), stream);
    hipMemsetAsync(degbuf, 0, (size_t)N1 * sizeof(float), stream);
    {
        long nthr = (long)E0 * 32;
        scatter_add_kernel<<<(int)((nthr + 255) / 256), 256, 0, stream>>>(
            feats, src0, dst0, msgbuf, degbuf, E0);
        sage_gemm_kernel<128, true><<<(N1 + 63) / 64, 256, 0, stream>>>(
            feats, msgbuf, degbuf, Wself0, Wneigh0, b0, h1, N1);
    }

    // ---- layer 1: 100K -> 20K, d 128->128, relu
    hipMemsetAsync(msgbuf, 0, (size_t)N2 * K_DIM * sizeof(float), stream);
    hipMemsetAsync(degbuf, 0, (size_t)N2 * sizeof(float), stream);
    {
        long nthr = (long)E1 * 32;
        scatter_add_kernel<<<(int)((nthr + 255) / 256), 256, 0, stream>>>(
            h1, src1, dst1, msgbuf, degbuf, E1);
        sage_gemm_kernel<128, true><<<(N2 + 63) / 64, 256, 0, stream>>>(
            h1, msgbuf, degbuf, Wself1, Wneigh1, b1, h2, N2);
    }

    // ---- layer 2: 20K -> 5K, d 128->64, no relu
    hipMemsetAsync(msgbuf, 0, (size_t)N3 * K_DIM * sizeof(float), stream);
    hipMemsetAsync(degbuf, 0, (size_t)N3 * sizeof(float), stream);
    {
        long nthr = (long)E2 * 32;
        scatter_add_kernel<<<(int)((nthr + 255) / 256), 256, 0, stream>>>(
            h2, src2, dst2, msgbuf, degbuf, E2);
        sage_gemm_kernel<64, false><<<(N3 + 63) / 64, 256, 0, stream>>>(
            h2, msgbuf, degbuf, Wself2, Wneigh2, b2, outp, N3);
    }
}

// Round 2
// 799.454 us; speedup vs baseline: 5.7707x; 5.7707x over previous
//
#include <hip/hip_runtime.h>

#define K_DIM 128

// ---------------------------------------------------------------------------
// CSR build: count degrees (int atomics)
// ---------------------------------------------------------------------------
__global__ __launch_bounds__(256)
void count_kernel(const int* __restrict__ dst, int* __restrict__ deg, int nE)
{
    int e = blockIdx.x * 256 + threadIdx.x;
    if (e < nE) atomicAdd(&deg[dst[e]], 1);
}

// per-256-block reduction of deg -> bsum[block]
__global__ __launch_bounds__(256)
void breduce_kernel(const int* __restrict__ deg, int* __restrict__ bsum, int n)
{
    __shared__ int sm[256];
    int i = blockIdx.x * 256 + threadIdx.x;
    sm[threadIdx.x] = (i < n) ? deg[i] : 0;
    __syncthreads();
    for (int s = 128; s > 0; s >>= 1) {
        if (threadIdx.x < s) sm[threadIdx.x] += sm[threadIdx.x + s];
        __syncthreads();
    }
    if (threadIdx.x == 0) bsum[blockIdx.x] = sm[0];
}

// single-block exclusive scan of bsum (nb <= 512)
__global__ __launch_bounds__(512)
void bscan_kernel(int* __restrict__ bsum, int nb)
{
    __shared__ int sm[512];
    int t = threadIdx.x;
    int v = (t < nb) ? bsum[t] : 0;
    sm[t] = v;
    __syncthreads();
    for (int s = 1; s < 512; s <<= 1) {
        int a = (t >= s) ? sm[t - s] : 0;
        __syncthreads();
        sm[t] += a;
        __syncthreads();
    }
    if (t < nb) bsum[t] = sm[t] - v;   // exclusive
}

// per-block scan of deg + block offset -> rowstart & cursor
__global__ __launch_bounds__(256)
void bwrite_kernel(const int* __restrict__ deg, const int* __restrict__ bsum,
                   int* __restrict__ rowstart, int* __restrict__ cursor, int n)
{
    __shared__ int sm[256];
    int t = threadIdx.x;
    int i = blockIdx.x * 256 + t;
    int v = (i < n) ? deg[i] : 0;
    sm[t] = v;
    __syncthreads();
    for (int s = 1; s < 256; s <<= 1) {
        int a = (t >= s) ? sm[t - s] : 0;
        __syncthreads();
        sm[t] += a;
        __syncthreads();
    }
    int excl = sm[t] - v + bsum[blockIdx.x];
    if (i < n) { rowstart[i] = excl; cursor[i] = excl; }
    if (i == n - 1) rowstart[n] = excl + v;
}

// bucket fill: csr[pos] = src
__global__ __launch_bounds__(256)
void fill_kernel(const int* __restrict__ src, const int* __restrict__ dst,
                 int* __restrict__ cursor, int* __restrict__ csr, int nE)
{
    int e = blockIdx.x * 256 + threadIdx.x;
    if (e < nE) {
        int pos = atomicAdd(&cursor[dst[e]], 1);
        csr[pos] = src[e];
    }
}

// W [ncol][128] -> Wt [128][ncol]
__global__ __launch_bounds__(256)
void transpose_w_kernel(const float* __restrict__ W, float* __restrict__ Wt, int ncol)
{
    int idx = blockIdx.x * 256 + threadIdx.x;
    if (idx < ncol * K_DIM) {
        int j = idx / K_DIM, k = idx - j * K_DIM;
        Wt[k * ncol + j] = W[j * K_DIM + k];
    }
}

// ---------------------------------------------------------------------------
// Fused SAGE layer: per 64-row block,
//   Phase A: gather neighbor mean into LDS (pull-mode via CSR)
//   Phase B: out = act(h @ WsT + mean @ WnT + b)
// ---------------------------------------------------------------------------
template<int NCOL, bool RELU>
__global__ __launch_bounds__(256)
void sage_fused_kernel(const float* __restrict__ h,
                       const int* __restrict__ csr,
                       const int* __restrict__ rowstart,
                       const float* __restrict__ WsT,   // [128][NCOL]
                       const float* __restrict__ WnT,   // [128][NCOL]
                       const float* __restrict__ bias,
                       float* __restrict__ out,
                       int n)
{
    constexpr int K    = 128;
    constexpr int KC   = 16;
    constexpr int ROWS = 64;
    constexpr int CT   = NCOL / 4;      // 32 or 16
    constexpr int RG   = 256 / CT;      // 8 or 16
    constexpr int RPT  = ROWS / RG;     // 8 or 4

    __shared__ float mean_s[ROWS][K];       // 32 KB
    __shared__ float Ws[KC][NCOL];
    __shared__ float Wn[KC][NCOL];
    __shared__ float hs[ROWS][KC + 4];      // padded vs bank conflicts

    const int t    = threadIdx.x;
    const int row0 = blockIdx.x * ROWS;

    // ---- Phase A: gather means into LDS (8 groups of 32 lanes, 8 rows each)
    {
        int g = t >> 5;
        int lane = t & 31;
        for (int r = g; r < ROWS; r += 8) {
            int gr = row0 + r;
            float4 acc = make_float4(0.f, 0.f, 0.f, 0.f);
            if (gr < n) {
                int s0 = rowstart[gr], s1 = rowstart[gr + 1];
                int e = s0;
                for (; e + 4 <= s1; e += 4) {        // 4-deep MLP unroll
                    int i0 = csr[e], i1 = csr[e + 1], i2 = csr[e + 2], i3 = csr[e + 3];
                    float4 v0 = reinterpret_cast<const float4*>(h + (long)i0 * K)[lane];
                    float4 v1 = reinterpret_cast<const float4*>(h + (long)i1 * K)[lane];
                    float4 v2 = reinterpret_cast<const float4*>(h + (long)i2 * K)[lane];
                    float4 v3 = reinterpret_cast<const float4*>(h + (long)i3 * K)[lane];
                    acc.x += (v0.x + v1.x) + (v2.x + v3.x);
                    acc.y += (v0.y + v1.y) + (v2.y + v3.y);
                    acc.z += (v0.z + v1.z) + (v2.z + v3.z);
                    acc.w += (v0.w + v1.w) + (v2.w + v3.w);
                }
                for (; e < s1; ++e) {
                    int i0 = csr[e];
                    float4 v0 = reinterpret_cast<const float4*>(h + (long)i0 * K)[lane];
                    acc.x += v0.x; acc.y += v0.y; acc.z += v0.z; acc.w += v0.w;
                }
                float rd = 1.0f / fmaxf((float)(s1 - s0), 1.0f);
                acc.x *= rd; acc.y *= rd; acc.z *= rd; acc.w *= rd;
            }
            reinterpret_cast<float4*>(&mean_s[r][0])[lane] = acc;
        }
    }

    // ---- Phase B: register-tiled GEMM
    const int ct = t % CT;
    const int rg = t / CT;
    const int c0 = ct * 4;

    float acc[RPT][4];
    #pragma unroll
    for (int r = 0; r < RPT; ++r)
        #pragma unroll
        for (int cc = 0; cc < 4; ++cc) acc[r][cc] = 0.0f;

    for (int kc = 0; kc < K; kc += KC) {
        __syncthreads();   // Phase A done (kc=0) / prev compute done

        // stage W chunk (coalesced float4; layouts are identical flat)
        #pragma unroll
        for (int idx = t; idx < KC * NCOL / 4; idx += 256) {
            reinterpret_cast<float4*>(&Ws[0][0])[idx] =
                reinterpret_cast<const float4*>(WsT + kc * NCOL)[idx];
            reinterpret_cast<float4*>(&Wn[0][0])[idx] =
                reinterpret_cast<const float4*>(WnT + kc * NCOL)[idx];
        }
        // stage h rows chunk: 256 threads = 64 rows x 4 float4s
        {
            int r = t >> 2, k4 = t & 3;
            int gr = row0 + r;
            float4 hv = make_float4(0.f, 0.f, 0.f, 0.f);
            if (gr < n)
                hv = reinterpret_cast<const float4*>(h + (long)gr * K + kc)[k4];
            *reinterpret_cast<float4*>(&hs[r][k4 * 4]) = hv;
        }
        __syncthreads();

        #pragma unroll
        for (int kk = 0; kk < KC; kk += 4) {
            float wsv[4][4], wnv[4][4];
            #pragma unroll
            for (int i = 0; i < 4; ++i) {
                float4 a = *reinterpret_cast<const float4*>(&Ws[kk + i][c0]);
                float4 b = *reinterpret_cast<const float4*>(&Wn[kk + i][c0]);
                wsv[i][0] = a.x; wsv[i][1] = a.y; wsv[i][2] = a.z; wsv[i][3] = a.w;
                wnv[i][0] = b.x; wnv[i][1] = b.y; wnv[i][2] = b.z; wnv[i][3] = b.w;
            }
            #pragma unroll
            for (int r = 0; r < RPT; ++r) {
                int row = rg * RPT + r;
                float4 hv = *reinterpret_cast<const float4*>(&hs[row][kk]);
                float4 mv = *reinterpret_cast<const float4*>(&mean_s[row][kc + kk]);
                float hvv[4] = {hv.x, hv.y, hv.z, hv.w};
                float mvv[4] = {mv.x, mv.y, mv.z, mv.w};
                #pragma unroll
                for (int cc = 0; cc < 4; ++cc) {
                    float a = acc[r][cc];
                    #pragma unroll
                    for (int i = 0; i < 4; ++i) {
                        a = fmaf(hvv[i], wsv[i][cc], a);
                        a = fmaf(mvv[i], wnv[i][cc], a);
                    }
                    acc[r][cc] = a;
                }
            }
        }
    }

    // epilogue
    #pragma unroll
    for (int r = 0; r < RPT; ++r) {
        int gr = row0 + rg * RPT + r;
        if (gr < n) {
            float4 o;
            float* op = reinterpret_cast<float*>(&o);
            #pragma unroll
            for (int cc = 0; cc < 4; ++cc) {
                float v = acc[r][cc] + bias[c0 + cc];
                if (RELU) v = fmaxf(v, 0.0f);
                op[cc] = v;
            }
            *reinterpret_cast<float4*>(out + (long)gr * NCOL + c0) = o;
        }
    }
}

// ---------------------------------------------------------------------------
// Workspace layout (floats):
//   h1:   [0, 12.8M)            layer-0 output (100K x 128)
//   h2:   [12.8M, 15.36M)       layer-1 output (20K x 128)
//   wsT:  [15.36M, +16384)      transposed Wself
//   wnT:  [15.376M, +16384)     transposed Wneigh
//   ints: [15.392768M ...)      csr(2M) deg(100K) rowstart(100K+1) cursor(100K) bsum(512)
// Total ~70.8 MB.
// ---------------------------------------------------------------------------
extern "C" void kernel_launch(void* const* d_in, const int* in_sizes, int n_in,
                              void* d_out, int out_size, void* d_ws, size_t ws_size,
                              hipStream_t stream)
{
    const float* feats   = (const float*)d_in[0];
    const int*   src0    = (const int*)d_in[1];
    const int*   dst0    = (const int*)d_in[2];
    const int*   src1    = (const int*)d_in[3];
    const int*   dst1    = (const int*)d_in[4];
    const int*   src2    = (const int*)d_in[5];
    const int*   dst2    = (const int*)d_in[6];
    const float* Wself0  = (const float*)d_in[10];
    const float* Wneigh0 = (const float*)d_in[11];
    const float* b0      = (const float*)d_in[12];
    const float* Wself1  = (const float*)d_in[13];
    const float* Wneigh1 = (const float*)d_in[14];
    const float* b1      = (const float*)d_in[15];
    const float* Wself2  = (const float*)d_in[16];
    const float* Wneigh2 = (const float*)d_in[17];
    const float* b2      = (const float*)d_in[18];

    const int E0 = in_sizes[1];
    const int E1 = in_sizes[3];
    const int E2 = in_sizes[5];
    const int N1 = 100000, N2 = 20000, N3 = 5000;

    float* ws  = (float*)d_ws;
    float* h1  = ws;
    float* h2  = ws + 12800000;
    float* wsT = ws + 15360000;
    float* wnT = wsT + 16384;
    int* ibuf      = (int*)(wnT + 16384);
    int* csr       = ibuf;
    int* degi      = csr + 2000000;
    int* rowstart  = degi + 100000;
    int* cursor    = rowstart + 100001;
    int* bsum      = cursor + 100000;

    auto run_layer = [&](const float* hsrc, const int* sE, const int* dE, int E, int n,
                         const float* Wself, const float* Wneigh, const float* bias,
                         float* outp, int ncol, bool relu) {
        hipMemsetAsync(degi, 0, (size_t)n * sizeof(int), stream);
        int nb = (n + 255) / 256;
        count_kernel<<<(E + 255) / 256, 256, 0, stream>>>(dE, degi, E);
        breduce_kernel<<<nb, 256, 0, stream>>>(degi, bsum, n);
        bscan_kernel<<<1, 512, 0, stream>>>(bsum, nb);
        bwrite_kernel<<<nb, 256, 0, stream>>>(degi, bsum, rowstart, cursor, n);
        fill_kernel<<<(E + 255) / 256, 256, 0, stream>>>(sE, dE, cursor, csr, E);
        transpose_w_kernel<<<(ncol * K_DIM + 255) / 256, 256, 0, stream>>>(Wself, wsT, ncol);
        transpose_w_kernel<<<(ncol * K_DIM + 255) / 256, 256, 0, stream>>>(Wneigh, wnT, ncol);
        int gb = (n + 63) / 64;
        if (ncol == 128) {
            sage_fused_kernel<128, true><<<gb, 256, 0, stream>>>(
                hsrc, csr, rowstart, wsT, wnT, bias, outp, n);
        } else {
            sage_fused_kernel<64, false><<<gb, 256, 0, stream>>>(
                hsrc, csr, rowstart, wsT, wnT, bias, outp, n);
        }
    };

    run_layer(feats, src0, dst0, E0, N1, Wself0, Wneigh0, b0, h1, 128, true);
    run_layer(h1,    src1, dst1, E1, N2, Wself1, Wneigh1, b1, h2, 128, true);
    run_layer(h2,    src2, dst2, E2, N3, Wself2, Wneigh2, b2, (float*)d_out, 64, false);
}

// Round 3
// 640.678 us; speedup vs baseline: 7.2008x; 1.2478x over previous
//
#include <hip/hip_runtime.h>

#define K_DIM 128

// ---------------------------------------------------------------------------
// Batched CSR build over all 3 layers.
// Row space: [0,100000) layer0 dst, [100000,120000) layer1, [120000,125000) l2.
// Edge space: [0,E0) l0, [E0,E0+E1) l1, [E0+E1,Etot) l2.
// ---------------------------------------------------------------------------
__global__ __launch_bounds__(256)
void count_all_kernel(const int* __restrict__ dst0, const int* __restrict__ dst1,
                      const int* __restrict__ dst2, int E0, int E1, int E2,
                      int* __restrict__ deg)
{
    int e = blockIdx.x * 256 + threadIdx.x;
    int row;
    if (e < E0)                row = dst0[e];
    else if (e < E0 + E1)      row = 100000 + dst1[e - E0];
    else if (e < E0 + E1 + E2) row = 120000 + dst2[e - E0 - E1];
    else return;
    atomicAdd(&deg[row], 1);
}

__global__ __launch_bounds__(256)
void breduce_kernel(const int* __restrict__ deg, int* __restrict__ bsum, int n)
{
    __shared__ int sm[256];
    int i = blockIdx.x * 256 + threadIdx.x;
    sm[threadIdx.x] = (i < n) ? deg[i] : 0;
    __syncthreads();
    for (int s = 128; s > 0; s >>= 1) {
        if (threadIdx.x < s) sm[threadIdx.x] += sm[threadIdx.x + s];
        __syncthreads();
    }
    if (threadIdx.x == 0) bsum[blockIdx.x] = sm[0];
}

__global__ __launch_bounds__(512)
void bscan_kernel(int* __restrict__ bsum, int nb)
{
    __shared__ int sm[512];
    int t = threadIdx.x;
    int v = (t < nb) ? bsum[t] : 0;
    sm[t] = v;
    __syncthreads();
    for (int s = 1; s < 512; s <<= 1) {
        int a = (t >= s) ? sm[t - s] : 0;
        __syncthreads();
        sm[t] += a;
        __syncthreads();
    }
    if (t < nb) bsum[t] = sm[t] - v;   // exclusive
}

__global__ __launch_bounds__(256)
void bwrite_kernel(const int* __restrict__ deg, const int* __restrict__ bsum,
                   int* __restrict__ rowstart, int* __restrict__ cursor, int n)
{
    __shared__ int sm[256];
    int t = threadIdx.x;
    int i = blockIdx.x * 256 + t;
    int v = (i < n) ? deg[i] : 0;
    sm[t] = v;
    __syncthreads();
    for (int s = 1; s < 256; s <<= 1) {
        int a = (t >= s) ? sm[t - s] : 0;
        __syncthreads();
        sm[t] += a;
        __syncthreads();
    }
    int excl = sm[t] - v + bsum[blockIdx.x];
    if (i < n) { rowstart[i] = excl; cursor[i] = excl; }
    if (i == n - 1) rowstart[n] = excl + v;
}

__global__ __launch_bounds__(256)
void fill_all_kernel(const int* __restrict__ src0, const int* __restrict__ src1,
                     const int* __restrict__ src2, const int* __restrict__ dst0,
                     const int* __restrict__ dst1, const int* __restrict__ dst2,
                     int E0, int E1, int E2,
                     int* __restrict__ cursor, int* __restrict__ csr)
{
    int e = blockIdx.x * 256 + threadIdx.x;
    int row, s;
    if (e < E0)                { row = dst0[e];                    s = src0[e]; }
    else if (e < E0 + E1)      { row = 100000 + dst1[e - E0];      s = src1[e - E0]; }
    else if (e < E0 + E1 + E2) { row = 120000 + dst2[e - E0 - E1]; s = src2[e - E0 - E1]; }
    else return;
    int pos = atomicAdd(&cursor[row], 1);
    csr[pos] = s;
}

// Transpose all 6 weight matrices into wT (layout documented in kernel_launch).
__global__ __launch_bounds__(256)
void transpose_all_kernel(const float* __restrict__ w0s, const float* __restrict__ w0n,
                          const float* __restrict__ w1s, const float* __restrict__ w1n,
                          const float* __restrict__ w2s, const float* __restrict__ w2n,
                          float* __restrict__ wT)
{
    int idx = blockIdx.x * 256 + threadIdx.x;
    if (idx >= 81920) return;
    const float* src; int off, ncol;
    if      (idx < 16384) { src = w0s; off = 0;     ncol = 128; }
    else if (idx < 32768) { src = w0n; off = 16384; ncol = 128; }
    else if (idx < 49152) { src = w1s; off = 32768; ncol = 128; }
    else if (idx < 65536) { src = w1n; off = 49152; ncol = 128; }
    else if (idx < 73728) { src = w2s; off = 65536; ncol = 64;  }
    else                  { src = w2n; off = 73728; ncol = 64;  }
    int local = idx - off;
    int j = local >> 7;       // row in W  (ncol rows of 128)
    int k = local & 127;      // k index
    wT[off + k * ncol + j] = src[j * K_DIM + k];
}

// ---------------------------------------------------------------------------
// Fused SAGE layer, ROWS=32 for 4 blocks/CU (50% occupancy):
//   Phase A: pull-mode gather of neighbor mean into LDS via CSR
//   Phase B: out = act(h @ WsT + mean @ WnT + b), register-tiled
// LDS: mean 16K + W 2*KC*NCOL*4 + hs ~2.5K  (~35 KB for NCOL=128)
// ---------------------------------------------------------------------------
template<int NCOL, bool RELU>
__global__ __launch_bounds__(256, 4)
void sage_fused_kernel(const float* __restrict__ h,
                       const int* __restrict__ csr,
                       const int* __restrict__ rs,     // rowstart + layer base
                       const float* __restrict__ WsT,  // [128][NCOL]
                       const float* __restrict__ WnT,  // [128][NCOL]
                       const float* __restrict__ bias,
                       float* __restrict__ out,
                       int n)
{
    constexpr int K    = 128;
    constexpr int KC   = 16;
    constexpr int ROWS = 32;
    constexpr int CT   = NCOL / 4;      // 32 or 16
    constexpr int RG   = 256 / CT;      // 8 or 16
    constexpr int RPT  = ROWS / RG;     // 4 or 2

    __shared__ float mean_s[ROWS][K];       // 16 KB
    __shared__ float Ws[KC][NCOL];
    __shared__ float Wn[KC][NCOL];
    __shared__ float hs[ROWS][KC + 4];

    const int t    = threadIdx.x;
    const int row0 = blockIdx.x * ROWS;

    // ---- Phase A: 8 groups of 32 lanes, 4 rows per group
    {
        int g = t >> 5;
        int lane = t & 31;
        for (int r = g; r < ROWS; r += 8) {
            int gr = row0 + r;
            float4 acc = make_float4(0.f, 0.f, 0.f, 0.f);
            if (gr < n) {
                int s0 = rs[gr], s1 = rs[gr + 1];
                int e = s0;
                for (; e + 4 <= s1; e += 4) {        // 4-deep MLP unroll
                    int i0 = csr[e], i1 = csr[e + 1], i2 = csr[e + 2], i3 = csr[e + 3];
                    float4 v0 = reinterpret_cast<const float4*>(h + (long)i0 * K)[lane];
                    float4 v1 = reinterpret_cast<const float4*>(h + (long)i1 * K)[lane];
                    float4 v2 = reinterpret_cast<const float4*>(h + (long)i2 * K)[lane];
                    float4 v3 = reinterpret_cast<const float4*>(h + (long)i3 * K)[lane];
                    acc.x += (v0.x + v1.x) + (v2.x + v3.x);
                    acc.y += (v0.y + v1.y) + (v2.y + v3.y);
                    acc.z += (v0.z + v1.z) + (v2.z + v3.z);
                    acc.w += (v0.w + v1.w) + (v2.w + v3.w);
                }
                for (; e < s1; ++e) {
                    int i0 = csr[e];
                    float4 v0 = reinterpret_cast<const float4*>(h + (long)i0 * K)[lane];
                    acc.x += v0.x; acc.y += v0.y; acc.z += v0.z; acc.w += v0.w;
                }
                float rd = 1.0f / fmaxf((float)(s1 - s0), 1.0f);
                acc.x *= rd; acc.y *= rd; acc.z *= rd; acc.w *= rd;
            }
            reinterpret_cast<float4*>(&mean_s[r][0])[lane] = acc;
        }
    }

    // ---- Phase B
    const int ct = t % CT;
    const int rg = t / CT;
    const int c0 = ct * 4;

    float acc[RPT][4];
    #pragma unroll
    for (int r = 0; r < RPT; ++r)
        #pragma unroll
        for (int cc = 0; cc < 4; ++cc) acc[r][cc] = 0.0f;

    for (int kc = 0; kc < K; kc += KC) {
        __syncthreads();   // Phase A done (kc=0) / prev compute done

        #pragma unroll
        for (int idx = t; idx < KC * NCOL / 4; idx += 256) {
            reinterpret_cast<float4*>(&Ws[0][0])[idx] =
                reinterpret_cast<const float4*>(WsT + kc * NCOL)[idx];
            reinterpret_cast<float4*>(&Wn[0][0])[idx] =
                reinterpret_cast<const float4*>(WnT + kc * NCOL)[idx];
        }
        if (t < ROWS * (KC / 4)) {       // 128 threads: 32 rows x 4 float4
            int r = t >> 2, k4 = t & 3;
            int gr = row0 + r;
            float4 hv = make_float4(0.f, 0.f, 0.f, 0.f);
            if (gr < n)
                hv = reinterpret_cast<const float4*>(h + (long)gr * K + kc)[k4];
            *reinterpret_cast<float4*>(&hs[r][k4 * 4]) = hv;
        }
        __syncthreads();

        #pragma unroll
        for (int kk = 0; kk < KC; kk += 4) {
            float wsv[4][4], wnv[4][4];
            #pragma unroll
            for (int i = 0; i < 4; ++i) {
                float4 a = *reinterpret_cast<const float4*>(&Ws[kk + i][c0]);
                float4 b = *reinterpret_cast<const float4*>(&Wn[kk + i][c0]);
                wsv[i][0] = a.x; wsv[i][1] = a.y; wsv[i][2] = a.z; wsv[i][3] = a.w;
                wnv[i][0] = b.x; wnv[i][1] = b.y; wnv[i][2] = b.z; wnv[i][3] = b.w;
            }
            #pragma unroll
            for (int r = 0; r < RPT; ++r) {
                int row = rg * RPT + r;
                float4 hv = *reinterpret_cast<const float4*>(&hs[row][kk]);
                float4 mv = *reinterpret_cast<const float4*>(&mean_s[row][kc + kk]);
                float hvv[4] = {hv.x, hv.y, hv.z, hv.w};
                float mvv[4] = {mv.x, mv.y, mv.z, mv.w};
                #pragma unroll
                for (int cc = 0; cc < 4; ++cc) {
                    float a = acc[r][cc];
                    #pragma unroll
                    for (int i = 0; i < 4; ++i) {
                        a = fmaf(hvv[i], wsv[i][cc], a);
                        a = fmaf(mvv[i], wnv[i][cc], a);
                    }
                    acc[r][cc] = a;
                }
            }
        }
    }

    #pragma unroll
    for (int r = 0; r < RPT; ++r) {
        int gr = row0 + rg * RPT + r;
        if (gr < n) {
            float4 o;
            float* op = reinterpret_cast<float*>(&o);
            #pragma unroll
            for (int cc = 0; cc < 4; ++cc) {
                float v = acc[r][cc] + bias[c0 + cc];
                if (RELU) v = fmaxf(v, 0.0f);
                op[cc] = v;
            }
            *reinterpret_cast<float4*>(out + (long)gr * NCOL + c0) = o;
        }
    }
}

// ---------------------------------------------------------------------------
// Workspace (floats):
//   h1:  [0, 12.8M)
//   h2:  [12.8M, 15.36M)
//   wT:  [15.36M, +81920)    [w0s|w0n|w1s|w1n|w2s|w2n] transposed
//   ints after: csr(2.5M) deg(125K) rowstart(125001) cursor(125K) bsum(512)
// Total ~73.2 MB.
// ---------------------------------------------------------------------------
extern "C" void kernel_launch(void* const* d_in, const int* in_sizes, int n_in,
                              void* d_out, int out_size, void* d_ws, size_t ws_size,
                              hipStream_t stream)
{
    const float* feats   = (const float*)d_in[0];
    const int*   src0    = (const int*)d_in[1];
    const int*   dst0    = (const int*)d_in[2];
    const int*   src1    = (const int*)d_in[3];
    const int*   dst1    = (const int*)d_in[4];
    const int*   src2    = (const int*)d_in[5];
    const int*   dst2    = (const int*)d_in[6];
    const float* Wself0  = (const float*)d_in[10];
    const float* Wneigh0 = (const float*)d_in[11];
    const float* b0      = (const float*)d_in[12];
    const float* Wself1  = (const float*)d_in[13];
    const float* Wneigh1 = (const float*)d_in[14];
    const float* b1      = (const float*)d_in[15];
    const float* Wself2  = (const float*)d_in[16];
    const float* Wneigh2 = (const float*)d_in[17];
    const float* b2      = (const float*)d_in[18];

    const int E0 = in_sizes[1];
    const int E1 = in_sizes[3];
    const int E2 = in_sizes[5];
    const int Etot = E0 + E1 + E2;           // 2.5M
    const int NTOT = 125000;                  // 100K + 20K + 5K
    const int N1 = 100000, N2 = 20000, N3 = 5000;

    float* ws  = (float*)d_ws;
    float* h1  = ws;
    float* h2  = ws + 12800000;
    float* wT  = ws + 15360000;
    int* csr      = (int*)(wT + 81920);
    int* degi     = csr + 2500000;
    int* rowstart = degi + 125000;
    int* cursor   = rowstart + 125001;
    int* bsum     = cursor + 125000;

    // ---- batched CSR build (all layers) + weight transpose
    hipMemsetAsync(degi, 0, (size_t)NTOT * sizeof(int), stream);
    count_all_kernel<<<(Etot + 255) / 256, 256, 0, stream>>>(
        dst0, dst1, dst2, E0, E1, E2, degi);
    int nb = (NTOT + 255) / 256;   // 489 <= 512
    breduce_kernel<<<nb, 256, 0, stream>>>(degi, bsum, NTOT);
    bscan_kernel<<<1, 512, 0, stream>>>(bsum, nb);
    bwrite_kernel<<<nb, 256, 0, stream>>>(degi, bsum, rowstart, cursor, NTOT);
    fill_all_kernel<<<(Etot + 255) / 256, 256, 0, stream>>>(
        src0, src1, src2, dst0, dst1, dst2, E0, E1, E2, cursor, csr);
    transpose_all_kernel<<<(81920 + 255) / 256, 256, 0, stream>>>(
        Wself0, Wneigh0, Wself1, Wneigh1, Wself2, Wneigh2, wT);

    // ---- layer 0: feats(500K) -> h1(100K), relu
    sage_fused_kernel<128, true><<<(N1 + 31) / 32, 256, 0, stream>>>(
        feats, csr, rowstart, wT, wT + 16384, b0, h1, N1);
    // ---- layer 1: h1 -> h2(20K), relu
    sage_fused_kernel<128, true><<<(N2 + 31) / 32, 256, 0, stream>>>(
        h1, csr, rowstart + 100000, wT + 32768, wT + 49152, b1, h2, N2);
    // ---- layer 2: h2 -> out(5K x 64), no relu
    sage_fused_kernel<64, false><<<(N3 + 31) / 32, 256, 0, stream>>>(
        h2, csr, rowstart + 120000, wT + 65536, wT + 73728, b2, (float*)d_out, N3);
}